// Round 1
// baseline (188.312 us; speedup 1.0000x reference)
//
#include <hip/hip_runtime.h>
#include <stdint.h>

#define NNODE 1000
#define NPAD  1024
#define KSP   200
#define DIM   64
#define BATCH 8

__global__ __launch_bounds__(256) void knn_edge_kernel(
    const float* __restrict__ locs,   // [B, N, 2]
    const float* __restrict__ emb,    // [B, N, 64]
    const float* __restrict__ W,      // [64]  (W[:,0])
    const float* __restrict__ bias,   // [64]
    float* __restrict__ out)
{
    __shared__ uint64_t keys[NPAD];   // (dist_bits << 32) | index
    __shared__ float sW[DIM], sB[DIM];
    __shared__ int selfpos;

    const int node = blockIdx.x;            // 0 .. B*N-1
    const int b    = node / NNODE;
    const int i    = node - b * NNODE;
    const int tid  = threadIdx.x;

    if (tid < DIM) { sW[tid] = W[tid]; sB[tid] = bias[tid]; }
    if (tid == 0)  selfpos = KSP + 1;       // "not found" sentinel

    const float2* loc = (const float2*)(locs + (size_t)b * NNODE * 2);
    const float2 self = loc[i];

    // --- distances: exact mul/add/sqrt rounding (match XLA: no fp contraction) ---
    for (int j = tid; j < NPAD; j += 256) {
        uint64_t key;
        if (j < NNODE) {
            float2 p = loc[j];
            float dx = __fsub_rn(self.x, p.x);
            float dy = __fsub_rn(self.y, p.y);
            float s  = __fadd_rn(__fmul_rn(dx, dx), __fmul_rn(dy, dy));
            float d  = __fsqrt_rn(s);
            key = ((uint64_t)__float_as_uint(d) << 32) | (uint32_t)j;
        } else {
            key = ~0ull;                    // pad sorts to the end
        }
        keys[j] = key;
    }

    // --- bitonic sort ascending, 1024 elems, 256 threads (2 pairs/thread/stage) ---
    for (int size = 2; size <= NPAD; size <<= 1) {
        for (int stride = size >> 1; stride > 0; stride >>= 1) {
            __syncthreads();
            #pragma unroll
            for (int tt = 0; tt < 2; ++tt) {
                int t   = tid + tt * 256;           // 0..511
                int idx = ((t / stride) * (stride << 1)) + (t % stride);
                int jdx = idx + stride;
                bool asc = ((idx & size) == 0);
                uint64_t a = keys[idx], c = keys[jdx];
                bool sw = asc ? (a > c) : (a < c);
                if (sw) { keys[idx] = c; keys[jdx] = a; }
            }
        }
    }
    __syncthreads();

    // --- locate self among first 201 (only one entry can match) ---
    if (tid <= KSP) {
        if ((uint32_t)(keys[tid] & 0xFFFFFFFFu) == (uint32_t)i) selfpos = tid;
    }
    __syncthreads();
    const int sp = selfpos;

    // --- output layout: x [B*N*64] | ei0 [E] | ei1 [E] | edge_emb [E*64] ---
    const size_t E    = (size_t)BATCH * NNODE * KSP;
    float* x_out = out;
    float* ei0   = out + (size_t)BATCH * NNODE * DIM;
    float* ei1   = ei0 + E;
    float* eemb  = ei1 + E;

    // x: copy this node's embedding row (64 floats = 16 float4)
    if (tid < 16) {
        const float4* s4 = (const float4*)(emb + (size_t)node * DIM);
        ((float4*)(x_out + (size_t)node * DIM))[tid] = s4[tid];
    }

    const size_t ebase = (size_t)node * KSP;

    // edge_index rows (as float; values < 8000 are exact)
    if (tid < KSP) {
        int slot = tid + (tid >= sp ? 1 : 0);
        uint64_t kk = keys[slot];
        ei0[ebase + tid] = (float)node;
        ei1[ebase + tid] = (float)(b * NNODE + (int)(uint32_t)(kk & 0xFFFFFFFFu));
    }

    // edge_emb: 200 edges x 64 ch = 3200 float4 stores, fully coalesced
    float4* em4 = (float4*)(eemb + ebase * DIM);
    for (int t = tid; t < KSP * (DIM / 4); t += 256) {
        int e  = t >> 4;                    // edge within node
        int c4 = (t & 15) << 2;             // channel group
        int slot = e + (e >= sp ? 1 : 0);
        float d = __uint_as_float((uint32_t)(keys[slot] >> 32));
        float4 v;
        v.x = fmaf(d, sW[c4 + 0], sB[c4 + 0]);
        v.y = fmaf(d, sW[c4 + 1], sB[c4 + 1]);
        v.z = fmaf(d, sW[c4 + 2], sB[c4 + 2]);
        v.w = fmaf(d, sW[c4 + 3], sB[c4 + 3]);
        em4[t] = v;
    }
}

extern "C" void kernel_launch(void* const* d_in, const int* in_sizes, int n_in,
                              void* d_out, int out_size, void* d_ws, size_t ws_size,
                              hipStream_t stream) {
    const float* locs = (const float*)d_in[0];
    const float* emb  = (const float*)d_in[1];
    const float* W    = (const float*)d_in[2];
    const float* bias = (const float*)d_in[3];
    float* out = (float*)d_out;

    knn_edge_kernel<<<BATCH * NNODE, 256, 0, stream>>>(locs, emb, W, bias, out);
}

// Round 2
// 108.677 us; speedup vs baseline: 1.7328x; 1.7328x over previous
//
#include <hip/hip_runtime.h>
#include <stdint.h>

#define NNODE 1000
#define KSP   200
#define DIM   64
#define BATCH 8
#define NBIN  256
#define MAXC  512

__global__ __launch_bounds__(256) void knn_edge_kernel(
    const float* __restrict__ locs,   // [B, N, 2]
    const float* __restrict__ emb,    // [B, N, 64]
    const float* __restrict__ W,      // [64]
    const float* __restrict__ bias,   // [64]
    float* __restrict__ out)
{
    __shared__ uint64_t keys[NNODE];  // (dist_bits << 32) | index, 8000 B
    __shared__ uint64_t cand[MAXC];   // 4096 B
    __shared__ int hist[NBIN];        // 1024 B
    __shared__ float sW[DIM], sB[DIM];
    __shared__ int s_bin, s_cnt, s_selfpos;

    const int node = blockIdx.x;
    const int b    = node / NNODE;
    const int i    = node - b * NNODE;
    const int tid  = threadIdx.x;

    if (tid < DIM) { sW[tid] = W[tid]; sB[tid] = bias[tid]; }
    hist[tid] = 0;                       // 256 threads cover 256 bins
    if (tid == 0) { s_cnt = 0; s_selfpos = KSP + 1; }
    __syncthreads();

    const float2* loc = (const float2*)(locs + (size_t)b * NNODE * 2);
    const float2 self = loc[i];

    // --- distances (exact XLA-matching rounding) + histogram ---
    for (int j = tid; j < NNODE; j += 256) {
        float2 p = loc[j];
        float dx = __fsub_rn(self.x, p.x);
        float dy = __fsub_rn(self.y, p.y);
        float s  = __fadd_rn(__fmul_rn(dx, dx), __fmul_rn(dy, dy));
        float d  = __fsqrt_rn(s);
        keys[j] = ((uint64_t)__float_as_uint(d) << 32) | (uint32_t)j;
        int q = (int)(d * 180.0f);       // monotone quantization, max ~254
        q = q > 255 ? 255 : q;
        atomicAdd(&hist[q], 1);
    }
    __syncthreads();

    // --- inclusive scan over 256 bins (Hillis-Steele) ---
    for (int off = 1; off < NBIN; off <<= 1) {
        int tmp = (tid >= off) ? hist[tid - off] : 0;
        __syncthreads();
        hist[tid] += tmp;
        __syncthreads();
    }
    // smallest bin with cumulative count >= 201
    if (hist[tid] >= KSP + 1 && (tid == 0 || hist[tid - 1] < KSP + 1)) s_bin = tid;
    __syncthreads();
    const int B = s_bin;

    // --- gather candidates with q <= B (expected ~210-230) ---
    for (int j = tid; j < NNODE; j += 256) {
        uint64_t kk = keys[j];
        float d = __uint_as_float((uint32_t)(kk >> 32));
        int q = (int)(d * 180.0f);
        q = q > 255 ? 255 : q;
        if (q <= B) {
            int pos = atomicAdd(&s_cnt, 1);
            if (pos < MAXC) cand[pos] = kk;
        }
    }
    __syncthreads();
    const int cnt = s_cnt;
    const int n_sort = (cnt > 256) ? MAXC : 256;
    for (int t = cnt + tid; t < n_sort; t += 256) cand[t] = ~0ull;  // pad
    __syncthreads();

    // --- exact bitonic sort ascending of n_sort packed keys ---
    for (int size = 2; size <= n_sort; size <<= 1) {
        for (int stride = size >> 1; stride > 0; stride >>= 1) {
            if (tid < (n_sort >> 1)) {
                int idx = ((tid / stride) * (stride << 1)) + (tid % stride);
                int jdx = idx + stride;
                bool asc = ((idx & size) == 0);
                uint64_t a = cand[idx], c = cand[jdx];
                bool sw = asc ? (a > c) : (a < c);
                if (sw) { cand[idx] = c; cand[jdx] = a; }
            }
            __syncthreads();
        }
    }

    // --- locate self among first 201 sorted entries ---
    if (tid <= KSP) {
        if ((uint32_t)(cand[tid] & 0xFFFFFFFFu) == (uint32_t)i) s_selfpos = tid;
    }
    __syncthreads();
    const int sp = s_selfpos;

    // --- output layout: x [B*N*64] | ei0 [E] | ei1 [E] | edge_emb [E*64] ---
    const size_t E = (size_t)BATCH * NNODE * KSP;
    float* x_out = out;
    float* ei0   = out + (size_t)BATCH * NNODE * DIM;
    float* ei1   = ei0 + E;
    float* eemb  = ei1 + E;

    if (tid < 16) {
        const float4* s4 = (const float4*)(emb + (size_t)node * DIM);
        ((float4*)(x_out + (size_t)node * DIM))[tid] = s4[tid];
    }

    const size_t ebase = (size_t)node * KSP;

    if (tid < KSP) {
        int slot = tid + (tid >= sp ? 1 : 0);
        uint64_t kk = cand[slot];
        ei0[ebase + tid] = (float)node;
        ei1[ebase + tid] = (float)(b * NNODE + (int)(uint32_t)(kk & 0xFFFFFFFFu));
    }

    // edge_emb: 200 edges x 64 ch = 3200 float4 coalesced stores
    float4* em4 = (float4*)(eemb + ebase * DIM);
    for (int t = tid; t < KSP * (DIM / 4); t += 256) {
        int e  = t >> 4;
        int c4 = (t & 15) << 2;
        int slot = e + (e >= sp ? 1 : 0);
        float d = __uint_as_float((uint32_t)(cand[slot] >> 32));
        float4 v;
        v.x = fmaf(d, sW[c4 + 0], sB[c4 + 0]);
        v.y = fmaf(d, sW[c4 + 1], sB[c4 + 1]);
        v.z = fmaf(d, sW[c4 + 2], sB[c4 + 2]);
        v.w = fmaf(d, sW[c4 + 3], sB[c4 + 3]);
        em4[t] = v;
    }
}

extern "C" void kernel_launch(void* const* d_in, const int* in_sizes, int n_in,
                              void* d_out, int out_size, void* d_ws, size_t ws_size,
                              hipStream_t stream) {
    const float* locs = (const float*)d_in[0];
    const float* emb  = (const float*)d_in[1];
    const float* W    = (const float*)d_in[2];
    const float* bias = (const float*)d_in[3];
    float* out = (float*)d_out;

    knn_edge_kernel<<<BATCH * NNODE, 256, 0, stream>>>(locs, emb, W, bias, out);
}